// Round 2
// baseline (432.211 us; speedup 1.0000x reference)
//
#include <hip/hip_runtime.h>
#include <hip/hip_fp16.h>

#define NG    32
#define DG    64
#define NPL   64
#define CPD   8            // cells per dim
#define NCELL (CPD*CPD*CPD)

// ---------------------------------------------------------------------------
// Pack kernel: [G][2][64][64][64] f32  ->  [G][64][64][64] half2 (c0,c1)
// ---------------------------------------------------------------------------
__global__ void pack_grids_kernel(const float* __restrict__ fg,
                                  __half2* __restrict__ pg, int total) {
    int idx = blockIdx.x * blockDim.x + threadIdx.x;
    if (idx >= total) return;
    int g = idx >> 18;                    // 64^3 = 2^18
    int v = idx & ((1 << 18) - 1);
    const float* base = fg + ((size_t)g << 19);
    float c0 = base[v];
    float c1 = base[(1 << 18) + v];
    pg[idx] = __floats2half2_rn(c0, c1);
}

// ---------------------------------------------------------------------------
// Histogram + cell-id: Morton code of 8^3 quantized position
// ---------------------------------------------------------------------------
__device__ __forceinline__ int morton8(int cx, int cy, int cz) {
    return  (cx & 1)        | ((cy & 1) << 1) | ((cz & 1) << 2)
         | (((cx >> 1) & 1) << 3) | (((cy >> 1) & 1) << 4) | (((cz >> 1) & 1) << 5)
         | (((cx >> 2) & 1) << 6) | (((cy >> 2) & 1) << 7) | (((cz >> 2) & 1) << 8);
}

__global__ void hist_kernel(const float* __restrict__ x, int N,
                            int* __restrict__ hist,
                            unsigned short* __restrict__ cellid) {
    __shared__ int lh[NCELL];
    for (int i = threadIdx.x; i < NCELL; i += blockDim.x) lh[i] = 0;
    __syncthreads();
    int n = blockIdx.x * blockDim.x + threadIdx.x;
    if (n < N) {
        float px = x[3 * n + 0];
        float py = x[3 * n + 1];
        float pz = x[3 * n + 2];
        int cx = min(max((int)((px + 1.0f) * (0.5f * CPD)), 0), CPD - 1);
        int cy = min(max((int)((py + 1.0f) * (0.5f * CPD)), 0), CPD - 1);
        int cz = min(max((int)((pz + 1.0f) * (0.5f * CPD)), 0), CPD - 1);
        int code = morton8(cx, cy, cz);
        cellid[n] = (unsigned short)code;
        atomicAdd(&lh[code], 1);
    }
    __syncthreads();
    for (int i = threadIdx.x; i < NCELL; i += blockDim.x) {
        int c = lh[i];
        if (c) atomicAdd(&hist[i], c);
    }
}

// ---------------------------------------------------------------------------
// Exclusive scan over 512 cell counts (one block, 512 threads)
// ---------------------------------------------------------------------------
__global__ void scan_kernel(const int* __restrict__ hist, int* __restrict__ cursor) {
    __shared__ int buf[NCELL];
    int t = threadIdx.x;
    buf[t] = hist[t];
    __syncthreads();
    #pragma unroll
    for (int off = 1; off < NCELL; off <<= 1) {
        int v = (t >= off) ? buf[t - off] : 0;
        __syncthreads();
        buf[t] += v;
        __syncthreads();
    }
    cursor[t] = (t == 0) ? 0 : buf[t - 1];
}

// ---------------------------------------------------------------------------
// Scatter: perm[sorted_pos] = original point index
// ---------------------------------------------------------------------------
__global__ void scatter_kernel(const unsigned short* __restrict__ cellid, int N,
                               int* __restrict__ cursor, int* __restrict__ perm) {
    int n = blockIdx.x * blockDim.x + threadIdx.x;
    if (n >= N) return;
    int c = cellid[n];
    int pos = atomicAdd(&cursor[c], 1);
    perm[pos] = n;
}

// ---------------------------------------------------------------------------
// Fused: trilinear sample (32 grids x 2ch) + 64-64-64-1 MLP
// MODE 0: packed half2 + sorted perm.  MODE 1: packed, unsorted.  MODE 2: raw.
// ---------------------------------------------------------------------------
template <int MODE>
__global__ __launch_bounds__(256)
void amrsrn_fused_kernel(const float* __restrict__ x,
                         const float* __restrict__ scales,
                         const float* __restrict__ trans,
                         const void*  __restrict__ gridsv,
                         const int*   __restrict__ perm,
                         const float* __restrict__ W0,
                         const float* __restrict__ b0,
                         const float* __restrict__ W1,
                         const float* __restrict__ b1,
                         const float* __restrict__ W2,
                         const float* __restrict__ b2,
                         float* __restrict__ out, int N, int swz)
{
    __shared__ float sW0[NPL * NPL];
    __shared__ float sW1[NPL * NPL];
    __shared__ float sW2[NPL];
    __shared__ float sb0[NPL];
    __shared__ float sb1[NPL];
    __shared__ float sA[NG * 3];
    __shared__ float sB[NG * 3];

    const int tid = threadIdx.x;
    for (int i = tid; i < NPL * NPL; i += 256) { sW0[i] = W0[i]; sW1[i] = W1[i]; }
    if (tid < NPL)   { sW2[tid] = W2[tid]; sb0[tid] = b0[tid]; sb1[tid] = b1[tid]; }
    if (tid < NG*3)  {
        // f = ((x*s + t)*INV148 + 1)*0.5*63 == x*A + B
        const float k = (1.0f / 1.48f) * 31.5f;
        sA[tid] = scales[tid] * k;
        sB[tid] = trans[tid] * k + 31.5f;
    }
    __syncthreads();

    int bid = blockIdx.x;
    int b   = swz ? ((bid & 7) * (gridDim.x >> 3) + (bid >> 3)) : bid;
    int i   = b * 256 + tid;
    if (i >= N) return;
    int n   = (MODE == 0) ? perm[i] : i;

    float px = x[3 * n + 0];
    float py = x[3 * n + 1];
    float pz = x[3 * n + 2];

    float feat[2 * NG];

    #pragma unroll
    for (int g = 0; g < NG; ++g) {
        float fx = fmaf(px, sA[3*g+0], sB[3*g+0]);
        float fy = fmaf(py, sA[3*g+1], sB[3*g+1]);
        float fz = fmaf(pz, sA[3*g+2], sB[3*g+2]);

        float c0 = 0.0f, c1 = 0.0f;
        if (fx > -1.0f && fx < 64.0f &&
            fy > -1.0f && fy < 64.0f &&
            fz > -1.0f && fz < 64.0f) {
            float flx = floorf(fx), fly = floorf(fy), flz = floorf(fz);
            int x0 = (int)flx, y0 = (int)fly, z0 = (int)flz;
            float wx = fx - flx, wy = fy - fly, wz = fz - flz;

            float wxa[2], wya[2], wza[2];
            int   xia[2], yia[2], zia[2];
            wxa[0] = (x0     >= 0  && x0     < DG) ? (1.0f - wx) : 0.0f;
            wxa[1] = (x0     >= -1 && x0 + 1 < DG) ? wx          : 0.0f;
            wya[0] = (y0     >= 0  && y0     < DG) ? (1.0f - wy) : 0.0f;
            wya[1] = (y0     >= -1 && y0 + 1 < DG) ? wy          : 0.0f;
            wza[0] = (z0     >= 0  && z0     < DG) ? (1.0f - wz) : 0.0f;
            wza[1] = (z0     >= -1 && z0 + 1 < DG) ? wz          : 0.0f;
            xia[0] = min(max(x0, 0), DG - 1);     xia[1] = min(max(x0 + 1, 0), DG - 1);
            yia[0] = min(max(y0, 0), DG - 1);     yia[1] = min(max(y0 + 1, 0), DG - 1);
            zia[0] = min(max(z0, 0), DG - 1);     zia[1] = min(max(z0 + 1, 0), DG - 1);

            #pragma unroll
            for (int dz = 0; dz < 2; ++dz) {
                #pragma unroll
                for (int dy = 0; dy < 2; ++dy) {
                    int   rowoff = (zia[dz] << 12) + (yia[dy] << 6);
                    float wyz    = wya[dy] * wza[dz];
                    #pragma unroll
                    for (int dx = 0; dx < 2; ++dx) {
                        float w = wxa[dx] * wyz;
                        if (MODE != 2) {
                            const __half2* pg = (const __half2*)gridsv;
                            __half2 hv = pg[(g << 18) + rowoff + xia[dx]];
                            float2  vf = __half22float2(hv);
                            c0 = fmaf(w, vf.x, c0);
                            c1 = fmaf(w, vf.y, c1);
                        } else {
                            const float* fr = (const float*)gridsv + ((size_t)g << 19);
                            c0 = fmaf(w, fr[rowoff + xia[dx]], c0);
                            c1 = fmaf(w, fr[(1 << 18) + rowoff + xia[dx]], c1);
                        }
                    }
                }
            }
        }
        feat[2 * g + 0] = c0;
        feat[2 * g + 1] = c1;
    }

    // ---- layer 0 ----
    float h1[NPL];
    #pragma unroll
    for (int j = 0; j < NPL; j += 2) {
        float a0 = 0.f, a1 = 0.f, a2 = 0.f, a3 = 0.f;
        const float* r0 = &sW0[j * NPL];
        const float* r1 = &sW0[(j + 1) * NPL];
        #pragma unroll
        for (int k = 0; k < NPL; k += 2) {
            a0 = fmaf(feat[k],     r0[k],     a0);
            a1 = fmaf(feat[k + 1], r0[k + 1], a1);
            a2 = fmaf(feat[k],     r1[k],     a2);
            a3 = fmaf(feat[k + 1], r1[k + 1], a3);
        }
        h1[j]     = fmaxf((a0 + a1) + sb0[j],     0.0f);
        h1[j + 1] = fmaxf((a2 + a3) + sb0[j + 1], 0.0f);
    }

    // ---- layer 1 (reuse feat) ----
    #pragma unroll
    for (int j = 0; j < NPL; j += 2) {
        float a0 = 0.f, a1 = 0.f, a2 = 0.f, a3 = 0.f;
        const float* r0 = &sW1[j * NPL];
        const float* r1 = &sW1[(j + 1) * NPL];
        #pragma unroll
        for (int k = 0; k < NPL; k += 2) {
            a0 = fmaf(h1[k],     r0[k],     a0);
            a1 = fmaf(h1[k + 1], r0[k + 1], a1);
            a2 = fmaf(h1[k],     r1[k],     a2);
            a3 = fmaf(h1[k + 1], r1[k + 1], a3);
        }
        feat[j]     = fmaxf((a0 + a1) + sb1[j],     0.0f);
        feat[j + 1] = fmaxf((a2 + a3) + sb1[j + 1], 0.0f);
    }

    // ---- layer 2 ----
    float a0 = 0.f, a1 = 0.f;
    #pragma unroll
    for (int k = 0; k < NPL; k += 2) {
        a0 = fmaf(feat[k],     sW2[k],     a0);
        a1 = fmaf(feat[k + 1], sW2[k + 1], a1);
    }
    out[n] = (a0 + a1) + b2[0];
}

// ---------------------------------------------------------------------------
extern "C" void kernel_launch(void* const* d_in, const int* in_sizes, int n_in,
                              void* d_out, int out_size, void* d_ws, size_t ws_size,
                              hipStream_t stream) {
    const float* x  = (const float*)d_in[0];
    const float* gs = (const float*)d_in[1];
    const float* gt = (const float*)d_in[2];
    const float* fg = (const float*)d_in[3];
    const float* W0 = (const float*)d_in[4];
    const float* b0 = (const float*)d_in[5];
    const float* W1 = (const float*)d_in[6];
    const float* b1 = (const float*)d_in[7];
    const float* W2 = (const float*)d_in[8];
    const float* b2 = (const float*)d_in[9];
    float* out = (float*)d_out;

    const int N    = out_size;
    const int nblk = (N + 255) / 256;
    const int swz  = (nblk % 8 == 0) ? 1 : 0;

    const size_t pg_bytes   = (size_t)NG * (1 << 18) * sizeof(__half2);  // 33.5 MB
    const size_t perm_bytes = (size_t)N * sizeof(int);
    const size_t cid_bytes  = (size_t)N * sizeof(unsigned short);
    const size_t hist_bytes = NCELL * sizeof(int);
    const size_t need_sort  = pg_bytes + perm_bytes + cid_bytes + 2 * hist_bytes;

    if (ws_size >= need_sort) {
        char* w = (char*)d_ws;
        __half2*        pg     = (__half2*)w;                 w += pg_bytes;
        int*            perm   = (int*)w;                     w += perm_bytes;
        unsigned short* cellid = (unsigned short*)w;          w += cid_bytes;
        int*            hist   = (int*)w;                     w += hist_bytes;
        int*            cursor = (int*)w;

        int total = NG << 18;
        pack_grids_kernel<<<(total + 255) / 256, 256, 0, stream>>>(fg, pg, total);
        hipMemsetAsync(hist, 0, hist_bytes, stream);
        hist_kernel<<<nblk, 256, 0, stream>>>(x, N, hist, cellid);
        scan_kernel<<<1, NCELL, 0, stream>>>(hist, cursor);
        scatter_kernel<<<nblk, 256, 0, stream>>>(cellid, N, cursor, perm);
        amrsrn_fused_kernel<0><<<nblk, 256, 0, stream>>>(
            x, gs, gt, pg, perm, W0, b0, W1, b1, W2, b2, out, N, swz);
    } else if (ws_size >= pg_bytes) {
        __half2* pg = (__half2*)d_ws;
        int total = NG << 18;
        pack_grids_kernel<<<(total + 255) / 256, 256, 0, stream>>>(fg, pg, total);
        amrsrn_fused_kernel<1><<<nblk, 256, 0, stream>>>(
            x, gs, gt, pg, nullptr, W0, b0, W1, b1, W2, b2, out, N, 0);
    } else {
        amrsrn_fused_kernel<2><<<nblk, 256, 0, stream>>>(
            x, gs, gt, fg, nullptr, W0, b0, W1, b1, W2, b2, out, N, 0);
    }
}

// Round 3
// 313.289 us; speedup vs baseline: 1.3796x; 1.3796x over previous
//
#include <hip/hip_runtime.h>
#include <hip/hip_fp16.h>

#define NG    32
#define DG    64
#define NPL   64
#define CPD   16
#define NCELL (CPD*CPD*CPD)    // 4096
#define HPAD  16               // ints per counter (64B line) to kill atomic contention
#define BS    512              // sort/fused block size

// ---------------------------------------------------------------------------
// Pack kernel: [G][2][64][64][64] f32  ->  [G][64][64][64] half2 (c0,c1)
// ---------------------------------------------------------------------------
__global__ void pack_grids_kernel(const float* __restrict__ fg,
                                  __half2* __restrict__ pg, int total) {
    int idx = blockIdx.x * blockDim.x + threadIdx.x;
    if (idx >= total) return;
    int g = idx >> 18;                    // 64^3 = 2^18
    int v = idx & ((1 << 18) - 1);
    const float* base = fg + ((size_t)g << 19);
    float c0 = base[v];
    float c1 = base[(1 << 18) + v];
    pg[idx] = __floats2half2_rn(c0, c1);
}

// ---------------------------------------------------------------------------
// Morton code, 4 bits per dim (16^3 cells)
// ---------------------------------------------------------------------------
__device__ __forceinline__ int morton16(int cx, int cy, int cz) {
    int m = 0;
    #pragma unroll
    for (int b = 0; b < 4; ++b) {
        m |= (((cx >> b) & 1) << (3 * b))
           | (((cy >> b) & 1) << (3 * b + 1))
           | (((cz >> b) & 1) << (3 * b + 2));
    }
    return m;
}

__device__ __forceinline__ int cell_of(float px, float py, float pz) {
    int cx = min(max((int)((px + 1.0f) * (0.5f * CPD)), 0), CPD - 1);
    int cy = min(max((int)((py + 1.0f) * (0.5f * CPD)), 0), CPD - 1);
    int cz = min(max((int)((pz + 1.0f) * (0.5f * CPD)), 0), CPD - 1);
    return morton16(cx, cy, cz);
}

// ---------------------------------------------------------------------------
// Histogram: per-block LDS hist, then one padded global atomic per distinct cell
// ---------------------------------------------------------------------------
__global__ __launch_bounds__(BS)
void hist_kernel(const float* __restrict__ x, int N, int* __restrict__ ghist) {
    __shared__ int lh[NCELL];
    for (int i = threadIdx.x; i < NCELL; i += BS) lh[i] = 0;
    __syncthreads();
    int n = blockIdx.x * BS + threadIdx.x;
    if (n < N) {
        int c = cell_of(x[3 * n], x[3 * n + 1], x[3 * n + 2]);
        atomicAdd(&lh[c], 1);
    }
    __syncthreads();
    for (int i = threadIdx.x; i < NCELL; i += BS) {
        int c = lh[i];
        if (c) atomicAdd(&ghist[i * HPAD], c);
    }
}

// ---------------------------------------------------------------------------
// Exclusive scan of 4096 padded counts -> padded cursor (single block, 1024 thr)
// ---------------------------------------------------------------------------
__global__ __launch_bounds__(1024)
void scan_kernel(const int* __restrict__ ghist, int* __restrict__ gcursor) {
    __shared__ int tsum[1024];
    int t = threadIdx.x;
    int v0 = ghist[(t * 4 + 0) * HPAD];
    int v1 = ghist[(t * 4 + 1) * HPAD];
    int v2 = ghist[(t * 4 + 2) * HPAD];
    int v3 = ghist[(t * 4 + 3) * HPAD];
    tsum[t] = v0 + v1 + v2 + v3;
    __syncthreads();
    #pragma unroll
    for (int off = 1; off < 1024; off <<= 1) {
        int u = (t >= off) ? tsum[t - off] : 0;
        __syncthreads();
        tsum[t] += u;
        __syncthreads();
    }
    int base = (t == 0) ? 0 : tsum[t - 1];
    gcursor[(t * 4 + 0) * HPAD] = base;  base += v0;
    gcursor[(t * 4 + 1) * HPAD] = base;  base += v1;
    gcursor[(t * 4 + 2) * HPAD] = base;  base += v2;
    gcursor[(t * 4 + 3) * HPAD] = base;
}

// ---------------------------------------------------------------------------
// Scatter: LDS ranks + one padded fetch-add per distinct cell per block;
// emits sorted float4(x, y, z, bitcast(point index))
// ---------------------------------------------------------------------------
__global__ __launch_bounds__(BS)
void scatter_kernel(const float* __restrict__ x, int N,
                    int* __restrict__ gcursor, float4* __restrict__ sorted) {
    __shared__ int cnt[NCELL];
    __shared__ int base[NCELL];
    int tid = threadIdx.x;
    for (int i = tid; i < NCELL; i += BS) cnt[i] = 0;
    __syncthreads();
    int n = blockIdx.x * BS + tid;
    float px = 0.f, py = 0.f, pz = 0.f;
    int c = 0, r = 0;
    bool act = (n < N);
    if (act) {
        px = x[3 * n]; py = x[3 * n + 1]; pz = x[3 * n + 2];
        c = cell_of(px, py, pz);
        r = atomicAdd(&cnt[c], 1);
    }
    __syncthreads();
    for (int i = tid; i < NCELL; i += BS) {
        int cc = cnt[i];
        base[i] = cc ? atomicAdd(&gcursor[i * HPAD], cc) : 0;
    }
    __syncthreads();
    if (act) {
        sorted[base[c] + r] = make_float4(px, py, pz, __int_as_float(n));
    }
}

// ---------------------------------------------------------------------------
// Fused: trilinear sample (32 grids x 2ch) + 64-64-64-1 MLP
// MODE 0: packed half2 + sorted float4 points.  MODE 1: packed, unsorted.
// MODE 2: raw f32 grids, unsorted.
// ---------------------------------------------------------------------------
template <int MODE>
__global__ __launch_bounds__(BS)
void amrsrn_fused_kernel(const float* __restrict__ x,
                         const float4* __restrict__ sorted,
                         const float* __restrict__ scales,
                         const float* __restrict__ trans,
                         const void*  __restrict__ gridsv,
                         const float* __restrict__ W0,
                         const float* __restrict__ b0,
                         const float* __restrict__ W1,
                         const float* __restrict__ b1,
                         const float* __restrict__ W2,
                         const float* __restrict__ b2,
                         float* __restrict__ out, int N, int swz)
{
    __shared__ float sW0[NPL * NPL];
    __shared__ float sW1[NPL * NPL];
    __shared__ float sW2[NPL];
    __shared__ float sb0[NPL];
    __shared__ float sb1[NPL];
    __shared__ float sA[NG * 3];
    __shared__ float sB[NG * 3];

    const int tid = threadIdx.x;
    for (int i = tid; i < NPL * NPL; i += BS) { sW0[i] = W0[i]; sW1[i] = W1[i]; }
    if (tid < NPL)   { sW2[tid] = W2[tid]; sb0[tid] = b0[tid]; sb1[tid] = b1[tid]; }
    if (tid < NG*3)  {
        // f = ((x*s + t)*INV148 + 1)*0.5*63 == x*A + B
        const float k = (1.0f / 1.48f) * 31.5f;
        sA[tid] = scales[tid] * k;
        sB[tid] = trans[tid] * k + 31.5f;
    }
    __syncthreads();

    int bid = blockIdx.x;
    int b   = swz ? ((bid & 7) * (gridDim.x >> 3) + (bid >> 3)) : bid;
    int i   = b * BS + tid;
    if (i >= N) return;

    float px, py, pz;
    int   n;
    if (MODE == 0) {
        float4 p = sorted[i];
        px = p.x; py = p.y; pz = p.z;
        n  = __float_as_int(p.w);
    } else {
        n  = i;
        px = x[3 * n + 0];
        py = x[3 * n + 1];
        pz = x[3 * n + 2];
    }

    float feat[2 * NG];

    #pragma unroll
    for (int g = 0; g < NG; ++g) {
        float fx = fmaf(px, sA[3*g+0], sB[3*g+0]);
        float fy = fmaf(py, sA[3*g+1], sB[3*g+1]);
        float fz = fmaf(pz, sA[3*g+2], sB[3*g+2]);

        float c0 = 0.0f, c1 = 0.0f;
        if (fx > -1.0f && fx < 64.0f &&
            fy > -1.0f && fy < 64.0f &&
            fz > -1.0f && fz < 64.0f) {
            float flx = floorf(fx), fly = floorf(fy), flz = floorf(fz);
            int x0 = (int)flx, y0 = (int)fly, z0 = (int)flz;
            float wx = fx - flx, wy = fy - fly, wz = fz - flz;

            float wxa[2], wya[2], wza[2];
            int   xia[2], yia[2], zia[2];
            wxa[0] = (x0     >= 0  && x0     < DG) ? (1.0f - wx) : 0.0f;
            wxa[1] = (x0     >= -1 && x0 + 1 < DG) ? wx          : 0.0f;
            wya[0] = (y0     >= 0  && y0     < DG) ? (1.0f - wy) : 0.0f;
            wya[1] = (y0     >= -1 && y0 + 1 < DG) ? wy          : 0.0f;
            wza[0] = (z0     >= 0  && z0     < DG) ? (1.0f - wz) : 0.0f;
            wza[1] = (z0     >= -1 && z0 + 1 < DG) ? wz          : 0.0f;
            xia[0] = min(max(x0, 0), DG - 1);     xia[1] = min(max(x0 + 1, 0), DG - 1);
            yia[0] = min(max(y0, 0), DG - 1);     yia[1] = min(max(y0 + 1, 0), DG - 1);
            zia[0] = min(max(z0, 0), DG - 1);     zia[1] = min(max(z0 + 1, 0), DG - 1);

            #pragma unroll
            for (int dz = 0; dz < 2; ++dz) {
                #pragma unroll
                for (int dy = 0; dy < 2; ++dy) {
                    int   rowoff = (zia[dz] << 12) + (yia[dy] << 6);
                    float wyz    = wya[dy] * wza[dz];
                    #pragma unroll
                    for (int dx = 0; dx < 2; ++dx) {
                        float w = wxa[dx] * wyz;
                        if (MODE != 2) {
                            const __half2* pg = (const __half2*)gridsv;
                            __half2 hv = pg[(g << 18) + rowoff + xia[dx]];
                            float2  vf = __half22float2(hv);
                            c0 = fmaf(w, vf.x, c0);
                            c1 = fmaf(w, vf.y, c1);
                        } else {
                            const float* fr = (const float*)gridsv + ((size_t)g << 19);
                            c0 = fmaf(w, fr[rowoff + xia[dx]], c0);
                            c1 = fmaf(w, fr[(1 << 18) + rowoff + xia[dx]], c1);
                        }
                    }
                }
            }
        }
        feat[2 * g + 0] = c0;
        feat[2 * g + 1] = c1;
    }

    // ---- layer 0 ----
    float h1[NPL];
    #pragma unroll
    for (int j = 0; j < NPL; j += 2) {
        float a0 = 0.f, a1 = 0.f, a2 = 0.f, a3 = 0.f;
        const float* r0 = &sW0[j * NPL];
        const float* r1 = &sW0[(j + 1) * NPL];
        #pragma unroll
        for (int k = 0; k < NPL; k += 2) {
            a0 = fmaf(feat[k],     r0[k],     a0);
            a1 = fmaf(feat[k + 1], r0[k + 1], a1);
            a2 = fmaf(feat[k],     r1[k],     a2);
            a3 = fmaf(feat[k + 1], r1[k + 1], a3);
        }
        h1[j]     = fmaxf((a0 + a1) + sb0[j],     0.0f);
        h1[j + 1] = fmaxf((a2 + a3) + sb0[j + 1], 0.0f);
    }

    // ---- layer 1 (reuse feat) ----
    #pragma unroll
    for (int j = 0; j < NPL; j += 2) {
        float a0 = 0.f, a1 = 0.f, a2 = 0.f, a3 = 0.f;
        const float* r0 = &sW1[j * NPL];
        const float* r1 = &sW1[(j + 1) * NPL];
        #pragma unroll
        for (int k = 0; k < NPL; k += 2) {
            a0 = fmaf(h1[k],     r0[k],     a0);
            a1 = fmaf(h1[k + 1], r0[k + 1], a1);
            a2 = fmaf(h1[k],     r1[k],     a2);
            a3 = fmaf(h1[k + 1], r1[k + 1], a3);
        }
        feat[j]     = fmaxf((a0 + a1) + sb1[j],     0.0f);
        feat[j + 1] = fmaxf((a2 + a3) + sb1[j + 1], 0.0f);
    }

    // ---- layer 2 ----
    float a0 = 0.f, a1 = 0.f;
    #pragma unroll
    for (int k = 0; k < NPL; k += 2) {
        a0 = fmaf(feat[k],     sW2[k],     a0);
        a1 = fmaf(feat[k + 1], sW2[k + 1], a1);
    }
    out[n] = (a0 + a1) + b2[0];
}

// ---------------------------------------------------------------------------
extern "C" void kernel_launch(void* const* d_in, const int* in_sizes, int n_in,
                              void* d_out, int out_size, void* d_ws, size_t ws_size,
                              hipStream_t stream) {
    const float* x  = (const float*)d_in[0];
    const float* gs = (const float*)d_in[1];
    const float* gt = (const float*)d_in[2];
    const float* fg = (const float*)d_in[3];
    const float* W0 = (const float*)d_in[4];
    const float* b0 = (const float*)d_in[5];
    const float* W1 = (const float*)d_in[6];
    const float* b1 = (const float*)d_in[7];
    const float* W2 = (const float*)d_in[8];
    const float* b2 = (const float*)d_in[9];
    float* out = (float*)d_out;

    const int N    = out_size;
    const int nblk = (N + BS - 1) / BS;
    const int swz  = (nblk % 8 == 0) ? 1 : 0;

    const size_t pg_bytes   = (size_t)NG * (1 << 18) * sizeof(__half2);   // 33.5 MB
    const size_t sort_bytes = (size_t)N * sizeof(float4);                 // 8 MB
    const size_t hist_bytes = (size_t)NCELL * HPAD * sizeof(int);         // 256 KB
    const size_t need_sort  = pg_bytes + sort_bytes + 2 * hist_bytes;

    if (ws_size >= need_sort) {
        char* w = (char*)d_ws;
        __half2* pg     = (__half2*)w;   w += pg_bytes;
        float4*  sorted = (float4*)w;    w += sort_bytes;
        int*     ghist  = (int*)w;       w += hist_bytes;
        int*     gcur   = (int*)w;

        int total = NG << 18;
        pack_grids_kernel<<<(total + 255) / 256, 256, 0, stream>>>(fg, pg, total);
        hipMemsetAsync(ghist, 0, hist_bytes, stream);
        hist_kernel<<<nblk, BS, 0, stream>>>(x, N, ghist);
        scan_kernel<<<1, 1024, 0, stream>>>(ghist, gcur);
        scatter_kernel<<<nblk, BS, 0, stream>>>(x, N, gcur, sorted);
        amrsrn_fused_kernel<0><<<nblk, BS, 0, stream>>>(
            x, sorted, gs, gt, pg, W0, b0, W1, b1, W2, b2, out, N, swz);
    } else if (ws_size >= pg_bytes) {
        __half2* pg = (__half2*)d_ws;
        int total = NG << 18;
        pack_grids_kernel<<<(total + 255) / 256, 256, 0, stream>>>(fg, pg, total);
        amrsrn_fused_kernel<1><<<nblk, BS, 0, stream>>>(
            x, nullptr, gs, gt, pg, W0, b0, W1, b1, W2, b2, out, N, 0);
    } else {
        amrsrn_fused_kernel<2><<<nblk, BS, 0, stream>>>(
            x, nullptr, gs, gt, fg, W0, b0, W1, b1, W2, b2, out, N, 0);
    }
}